// Round 16
// baseline (59.699 us; speedup 1.0000x reference)
//
#include <hip/hip_runtime.h>
#include <hip/hip_bf16.h>

// Fused: cvt(fp32->bf16) ; qkv-GEMM emitting Q(pre-scaled)/K/V in attn-native
// tiled layouts ; blockmasked 16-head attention with 32x32 MFMA, swapped QK^T,
// in-register softmax, q64 blocks (each K/V load feeds TWO Q-subtiles -> 2x
// arithmetic intensity), kv-split x4 ; out = attn @ w_fc^T.
// L=1152, D=1024, NH=16, DH=64, N_PC=1024.

typedef short bf16x8 __attribute__((ext_vector_type(8)));
typedef float f32x4 __attribute__((ext_vector_type(4)));
typedef float f32x16 __attribute__((ext_vector_type(16)));

#define L_SEQ   1152
#define NPC     1024
#define DMODEL  1024
#define TD      3072
#define NHEADS  16
#define DHEAD   64
#define NT32    36

__device__ __forceinline__ void gld_lds16(const void* g, void* l) {
  __builtin_amdgcn_global_load_lds((const __attribute__((address_space(1))) void*)g,
                                   (__attribute__((address_space(3))) void*)l,
                                   16, 0, 0);
}

template <int N>
__device__ __forceinline__ void s_wait_vmcnt() {
  if constexpr (N == 0)       asm volatile("s_waitcnt vmcnt(0)" ::: "memory");
  else if constexpr (N == 2)  asm volatile("s_waitcnt vmcnt(2)" ::: "memory");
  else if constexpr (N == 4)  asm volatile("s_waitcnt vmcnt(4)" ::: "memory");
  else if constexpr (N == 6)  asm volatile("s_waitcnt vmcnt(6)" ::: "memory");
  else if constexpr (N == 8)  asm volatile("s_waitcnt vmcnt(8)" ::: "memory");
  else if constexpr (N == 12) asm volatile("s_waitcnt vmcnt(12)" ::: "memory");
  else if constexpr (N == 16) asm volatile("s_waitcnt vmcnt(16)" ::: "memory");
  else static_assert(N == 0, "add vmcnt case");
}

// ---------------- fp32 -> bf16, all three tensors in one launch ----------------
__global__ void cvt_all(const float* __restrict__ x, const float* __restrict__ wq,
                        const float* __restrict__ wf,
                        __hip_bfloat16* __restrict__ xb,
                        __hip_bfloat16* __restrict__ wqb,
                        __hip_bfloat16* __restrict__ wfb) {
  const int NX = 1152 * 1024 / 4, NQ = 3072 * 1024 / 4;
  int i = blockIdx.x * blockDim.x + threadIdx.x;
  const float* s; __hip_bfloat16* d; int j;
  if (i < NX) { s = x; d = xb; j = i; }
  else if (i < NX + NQ) { s = wq; d = wqb; j = i - NX; }
  else { s = wf; d = wfb; j = i - NX - NQ; }
  float4 v = ((const float4*)s)[j];
  __align__(8) __hip_bfloat16 o[4];
  o[0] = __float2bfloat16(v.x);
  o[1] = __float2bfloat16(v.y);
  o[2] = __float2bfloat16(v.z);
  o[3] = __float2bfloat16(v.w);
  *(uint2*)&d[(size_t)j * 4] = *(const uint2*)o;
}

// ---------------- bf16 GEMM: C[M,N] = A[M,K] * B[N,K]^T ----------------
// Identical to R12 (3-buffer cyclic pipeline, counted vmcnt, XOR-swizzled
// staging, XCD-swizzled flat grid; MODE1 emits Q(pre-scaled)/K/V tiled).
template <int BM, int BN, int MODE, typename OT>
__global__ __launch_bounds__(256) void gemm_bt(
    const __hip_bfloat16* __restrict__ A,
    const __hip_bfloat16* __restrict__ B,
    OT* __restrict__ C, __hip_bfloat16* __restrict__ kT,
    __hip_bfloat16* __restrict__ vT,
    int M, int N, int K, int MT) {
  constexpr int WMT = BM / 2, WNT = BN / 2;
  constexpr int MI = WMT / 16, NI = WNT / 16;
  constexpr int ACH = BM * 8, BCH = BN * 8;
  constexpr int S = (ACH + BCH) / 256;
  __shared__ __align__(16) __hip_bfloat16 As[3][BM * 64];
  __shared__ __align__(16) __hip_bfloat16 Bs[3][BN * 64];

  const int tid = threadIdx.x, lane = tid & 63, w = tid >> 6;
  const int wm = w >> 1, wn = w & 1, l15 = lane & 15, lg = lane >> 4;
  const int chunk = (int)gridDim.x >> 3;
  const int wgid = ((int)blockIdx.x & 7) * chunk + ((int)blockIdx.x >> 3);
  const int m0 = (wgid % MT) * BM, n0 = (wgid / MT) * BN;

  f32x4 acc[MI][NI] = {};

  auto stage = [&](int b, int kt) {
    const __hip_bfloat16* Ag = A + (size_t)m0 * K + kt;
    const __hip_bfloat16* Bg = B + (size_t)n0 * K + kt;
#pragma unroll
    for (int c = tid; c < ACH; c += 256) {
      int r = c >> 3, gc = (c & 7) ^ (r & 7);
      gld_lds16(Ag + (size_t)r * K + gc * 8, &As[b][c * 8]);
    }
#pragma unroll
    for (int c = tid; c < BCH; c += 256) {
      int r = c >> 3, gc = (c & 7) ^ (r & 7);
      gld_lds16(Bg + (size_t)r * K + gc * 8, &Bs[b][c * 8]);
    }
  };

  const int NK = K >> 6;
  stage(0, 0);
  stage(1, 64);
  stage(2, 128);

  int buf = 0;
  for (int t = 0; t < NK; ++t) {
    if (t < NK - 2)       s_wait_vmcnt<2 * S>();
    else if (t == NK - 2) s_wait_vmcnt<S>();
    else                  s_wait_vmcnt<0>();
    __builtin_amdgcn_s_barrier();
    __builtin_amdgcn_sched_barrier(0);

#pragma unroll
    for (int kk = 0; kk < 2; ++kk) {
      bf16x8 af[MI], bfr[NI];
#pragma unroll
      for (int i = 0; i < MI; ++i) {
        int r = wm * WMT + i * 16 + l15;
        af[i] = *(const bf16x8*)&As[buf][(r * 8 + (((kk << 2) + lg) ^ (r & 7))) * 8];
      }
#pragma unroll
      for (int i = 0; i < NI; ++i) {
        int r = wn * WNT + i * 16 + l15;
        bfr[i] = *(const bf16x8*)&Bs[buf][(r * 8 + (((kk << 2) + lg) ^ (r & 7))) * 8];
      }
#pragma unroll
      for (int mi = 0; mi < MI; ++mi)
#pragma unroll
        for (int ni = 0; ni < NI; ++ni)
          acc[mi][ni] = __builtin_amdgcn_mfma_f32_16x16x32_bf16(
              af[mi], bfr[ni], acc[mi][ni], 0, 0, 0);
    }

    __builtin_amdgcn_sched_barrier(0);
    __builtin_amdgcn_s_barrier();
    __builtin_amdgcn_sched_barrier(0);
    if (t + 3 < NK) stage(buf, (t + 3) * 64);
    buf = (buf + 1 == 3) ? 0 : buf + 1;
  }

  // C/D layout (HW-verified m89): col = lane&15, row = (lane>>4)*4 + reg
  if constexpr (MODE == 0) {
#pragma unroll
    for (int mi = 0; mi < MI; ++mi)
#pragma unroll
      for (int ni = 0; ni < NI; ++ni) {
        int rb = m0 + wm * WMT + mi * 16 + lg * 4;
        int cb = n0 + wn * WNT + ni * 16 + l15;
#pragma unroll
        for (int r = 0; r < 4; ++r)
          C[(size_t)(rb + r) * N + cb] = acc[mi][ni][r];
      }
  } else if (n0 < 2 * DMODEL) {          // Q or K region -> tiled Q/K layout
    const bool isQ = (n0 < DMODEL);
    const float scl = isQ ? 0.18033688f : 1.0f;   // 0.125*log2(e)
    __hip_bfloat16* dst = isQ ? (__hip_bfloat16*)C : kT;
    const int nb = isQ ? n0 : (n0 - DMODEL);
    constexpr int TS2 = BN + 8;
    __hip_bfloat16* T = &As[0][0];
    __syncthreads();
#pragma unroll
    for (int mi = 0; mi < MI; ++mi)
#pragma unroll
      for (int ni = 0; ni < NI; ++ni) {
        int ml = wm * WMT + mi * 16 + lg * 4;
        int nl = wn * WNT + ni * 16 + l15;
#pragma unroll
        for (int r = 0; r < 4; ++r)
          T[(ml + r) * TS2 + nl] = __float2bfloat16(acc[mi][ni][r] * scl);
      }
    __syncthreads();
#pragma unroll
    for (int c = tid; c < (BM * BN) / 8; c += 256) {
      int ml = c >> 4, dc = c & 15;
      bf16x8 v = *(const bf16x8*)&T[ml * TS2 + dc * 8];
      int dfull = nb + dc * 8;
      int hh = dfull >> 6, dh = dfull & 63;
      int g = m0 + ml;
      size_t off = ((size_t)(hh * NT32 + (g >> 5))) * 2048 +
                   (size_t)((dh >> 4) * 64 + ((dh >> 3) & 1) * 32 + (g & 31)) * 8;
      *(bf16x8*)&dst[off] = v;
    }
  } else {                               // V region -> tiled V layout
    constexpr int TS = BM + 8;
    __hip_bfloat16* T = &As[0][0];
    __syncthreads();
#pragma unroll
    for (int mi = 0; mi < MI; ++mi)
#pragma unroll
      for (int ni = 0; ni < NI; ++ni) {
        int e = wn * WNT + ni * 16 + l15;
        int l = wm * WMT + mi * 16 + lg * 4;
        __align__(8) __hip_bfloat16 o4[4];
#pragma unroll
        for (int r = 0; r < 4; ++r) o4[r] = __float2bfloat16(acc[mi][ni][r]);
        *(uint2*)&T[e * TS + l] = *(const uint2*)o4;
      }
    __syncthreads();
#pragma unroll
    for (int c = tid; c < (BN * BM) / 8; c += 256) {
      int dl = c >> 3, kvc = (c & 7) * 8;
      bf16x8 v = *(const bf16x8*)&T[dl * TS + kvc];
      int dfull = n0 - 2 * DMODEL + dl;
      int hh = dfull >> 6, dh = dfull & 63;
      int kvg = m0 + kvc;
      size_t off = ((size_t)(hh * NT32 + (kvg >> 5))) * 2048 +
                   (size_t)((((kvg >> 4) & 1) * 2 + (dh >> 5)) * 64 +
                            ((kvg >> 3) & 1) * 32 + (dh & 31)) * 8;
      *(bf16x8*)&vT[off] = v;
    }
  }
}

// ---------------- 32x32-MFMA attention: q64 blocks, kv-split x4 ----------------
// grid 288 XCD-swizzled (h = wgid/18, q64-tile = wgid%18). 256 threads = 4
// waves; wave w owns kv-quarter for BOTH q-subtiles -> each K/V load feeds
// 2x QK + 2x PV. Single-buffered K/V regs, consume-then-reload ordering.
__global__ __launch_bounds__(256) void attn64(
    const __hip_bfloat16* __restrict__ qT,
    const __hip_bfloat16* __restrict__ kT,
    const __hip_bfloat16* __restrict__ vT,
    __hip_bfloat16* __restrict__ attnb) {
  const int wgid = ((int)blockIdx.x & 7) * 36 + ((int)blockIdx.x >> 3);
  const int h = wgid / 18, qt = wgid % 18;     // q64 tile
  const int q0 = qt * 64;
  const int tid = threadIdx.x, lane = tid & 63, w = tid >> 6;  // w in [0,4)
  const int l31 = lane & 31, hi = lane >> 5;

  __shared__ __align__(16) float Osh[4][64][68];   // 69.6 KB
  __shared__ float Lsh[4][64];

  const __hip_bfloat16* qtpLo = qT + ((size_t)h * NT32 + qt * 2) * 2048;
  const __hip_bfloat16* qtpHi = qtpLo + 2048;
  bf16x8 qLo[4], qHi[4];
#pragma unroll
  for (int c = 0; c < 4; ++c) {
    qLo[c] = *(const bf16x8*)(qtpLo + (c * 64 + lane) * 8);
    qHi[c] = *(const bf16x8*)(qtpHi + (c * 64 + lane) * 8);
  }

  const int limLo = (q0 + l31 < NPC) ? NPC : (q0 + l31 + 1);
  const int limHi = (q0 + 32 + l31 < NPC) ? NPC : (q0 + 32 + l31 + 1);
  const int nst = (q0 + 64 <= NPC) ? 32 : ((q0 + 64) >> 5);   // 32, 34, 36
  const int tbeg = (w * nst) >> 2, tend = ((w + 1) * nst) >> 2;

  const __hip_bfloat16* ktp = kT + (size_t)h * NT32 * 2048;
  const __hip_bfloat16* vtp = vT + (size_t)h * NT32 * 2048;

  float lsumLo = 0.f, lsumHi = 0.f;
  f32x16 oLoA = {}, oLoB = {}, oHiA = {}, oHiB = {};
  bf16x8 kA[4], vA[4];
  float p[16];
  bf16x8 pa0, pa1;

  auto LDk = [&](int t) {
    const __hip_bfloat16* kp = ktp + (size_t)t * 2048;
#pragma unroll
    for (int c = 0; c < 4; ++c) kA[c] = *(const bf16x8*)(kp + (c * 64 + lane) * 8);
  };
  auto LDv = [&](int t) {
    const __hip_bfloat16* vp = vtp + (size_t)t * 2048;
#pragma unroll
    for (int c = 0; c < 4; ++c) vA[c] = *(const bf16x8*)(vp + (c * 64 + lane) * 8);
  };

  auto QK = [&](bf16x8 (&qf)[4]) -> f32x16 {
    f32x16 S0 = {}, S1 = {};
    __builtin_amdgcn_s_setprio(1);
    S0 = __builtin_amdgcn_mfma_f32_32x32x16_bf16(kA[0], qf[0], S0, 0, 0, 0);
    S1 = __builtin_amdgcn_mfma_f32_32x32x16_bf16(kA[2], qf[2], S1, 0, 0, 0);
    S0 = __builtin_amdgcn_mfma_f32_32x32x16_bf16(kA[1], qf[1], S0, 0, 0, 0);
    S1 = __builtin_amdgcn_mfma_f32_32x32x16_bf16(kA[3], qf[3], S1, 0, 0, 0);
    __builtin_amdgcn_s_setprio(0);
    return S0 + S1;
  };

  auto FIN = [&](const f32x16& S, int t, int lim, float& lsum) {
#pragma unroll
    for (int r = 0; r < 16; ++r) p[r] = __builtin_amdgcn_exp2f(S[r]);
    const int kv0 = t << 5;
    if (kv0 >= NPC) {
#pragma unroll
      for (int r = 0; r < 16; ++r) {
        int kv = kv0 + (r & 3) + 8 * (r >> 2) + 4 * hi;
        if (kv >= lim) p[r] = 0.f;
      }
    }
#pragma unroll
    for (int r = 0; r < 16; ++r) lsum += p[r];
  };

  auto PACK = [&]() {
    unsigned W[8];
#pragma unroll
    for (int g = 0; g < 2; ++g) {
      unsigned x0, x1, y0, y1;
      asm("v_cvt_pk_bf16_f32 %0, %1, %2" : "=v"(x0) : "v"(p[g*8+0]), "v"(p[g*8+1]));
      asm("v_cvt_pk_bf16_f32 %0, %1, %2" : "=v"(x1) : "v"(p[g*8+4]), "v"(p[g*8+5]));
      asm("v_cvt_pk_bf16_f32 %0, %1, %2" : "=v"(y0) : "v"(p[g*8+2]), "v"(p[g*8+3]));
      asm("v_cvt_pk_bf16_f32 %0, %1, %2" : "=v"(y1) : "v"(p[g*8+6]), "v"(p[g*8+7]));
      asm("v_permlane32_swap_b32 %0, %1" : "+v"(x0), "+v"(x1));
      asm("v_permlane32_swap_b32 %0, %1" : "+v"(y0), "+v"(y1));
      W[g*4+0] = x0; W[g*4+1] = y0; W[g*4+2] = x1; W[g*4+3] = y1;
    }
    __builtin_memcpy(&pa0, &W[0], 16);
    __builtin_memcpy(&pa1, &W[4], 16);
  };

  auto PV = [&](f32x16& oA, f32x16& oB) {
    __builtin_amdgcn_s_setprio(1);
    oA = __builtin_amdgcn_mfma_f32_32x32x16_bf16(pa0, vA[0], oA, 0, 0, 0);
    oB = __builtin_amdgcn_mfma_f32_32x32x16_bf16(pa0, vA[1], oB, 0, 0, 0);
    oA = __builtin_amdgcn_mfma_f32_32x32x16_bf16(pa1, vA[2], oA, 0, 0, 0);
    oB = __builtin_amdgcn_mfma_f32_32x32x16_bf16(pa1, vA[3], oB, 0, 0, 0);
    __builtin_amdgcn_s_setprio(0);
  };

  LDk(tbeg); LDv(tbeg);
  for (int st = tbeg; st < tend; ++st) {
    f32x16 Sl = QK(qLo);
    f32x16 Sh = QK(qHi);                  // kA free after this
    if (st + 1 < tend) LDk(st + 1);       // load hides under FIN/PACK/PV below
    FIN(Sl, st, limLo, lsumLo); PACK(); PV(oLoA, oLoB);
    FIN(Sh, st, limHi, lsumHi); PACK(); PV(oHiA, oHiB);   // vA free
    if (st + 1 < tend) LDv(st + 1);       // hides under next tile's QK
  }

  lsumLo += __shfl_xor(lsumLo, 32);
  lsumHi += __shfl_xor(lsumHi, 32);

  // publish partials (no-max softmax: additive merge of 4 kv-quarters)
#pragma unroll
  for (int r = 0; r < 16; ++r) {
    int qr = (r & 3) + 8 * (r >> 2) + 4 * hi;
    Osh[w][qr][l31]      = oLoA[r];
    Osh[w][qr][32 + l31] = oLoB[r];
    Osh[w][32 + qr][l31]      = oHiA[r];
    Osh[w][32 + qr][32 + l31] = oHiB[r];
  }
  if (lane < 32) {
    Lsh[w][l31] = lsumLo;
    Lsh[w][32 + l31] = lsumHi;
  }
  __syncthreads();

  // 256 threads: each writes 16 d-elems of one of 64 q-rows
  const int qq = tid >> 2, d16 = (tid & 3) * 16;
  float inv = 1.0f / (Lsh[0][qq] + Lsh[1][qq] + Lsh[2][qq] + Lsh[3][qq]);
#pragma unroll
  for (int g = 0; g < 2; ++g) {
    __align__(16) __hip_bfloat16 o8[8];
#pragma unroll
    for (int j = 0; j < 8; ++j) {
      float o = Osh[0][qq][d16 + g * 8 + j] + Osh[1][qq][d16 + g * 8 + j] +
                Osh[2][qq][d16 + g * 8 + j] + Osh[3][qq][d16 + g * 8 + j];
      o8[j] = __float2bfloat16(o * inv);
    }
    *(int4*)&attnb[(size_t)(q0 + qq) * DMODEL + h * DHEAD + d16 + g * 8] =
        *(const int4*)o8;
  }
}

// ---------------- launch ----------------
extern "C" void kernel_launch(void* const* d_in, const int* in_sizes, int n_in,
                              void* d_out, int out_size, void* d_ws, size_t ws_size,
                              hipStream_t stream) {
  const float* x     = (const float*)d_in[0];
  const float* w_qkv = (const float*)d_in[1];
  const float* w_fc  = (const float*)d_in[2];
  float* out = (float*)d_out;

  char* ws = (char*)d_ws;
  __hip_bfloat16* xb    = (__hip_bfloat16*)(ws + 0);
  __hip_bfloat16* wqkvb = (__hip_bfloat16*)(ws + 2359296);
  __hip_bfloat16* wfcb  = (__hip_bfloat16*)(ws + 8650752);
  __hip_bfloat16* qTb   = (__hip_bfloat16*)(ws + 10747904);
  __hip_bfloat16* kTb   = (__hip_bfloat16*)(ws + 13107200);
  __hip_bfloat16* vTb   = (__hip_bfloat16*)(ws + 15466496);
  __hip_bfloat16* attnb = (__hip_bfloat16*)(ws + 17825792);

  cvt_all<<<5248, 256, 0, stream>>>(x, w_qkv, w_fc, xb, wqkvb, wfcb);

  gemm_bt<64, 128, 1, __hip_bfloat16><<<432, 256, 0, stream>>>(
      xb, wqkvb, qTb, kTb, vTb, L_SEQ, TD, DMODEL, 18);

  attn64<<<288, 256, 0, stream>>>(qTb, kTb, vTb, attnb);

  gemm_bt<64, 64, 0, float><<<288, 256, 0, stream>>>(
      attnb, wfcb, out, nullptr, nullptr, L_SEQ, DMODEL, DMODEL, 18);
}

// Round 17
// 50.723 us; speedup vs baseline: 1.1769x; 1.1769x over previous
//
#include <hip/hip_runtime.h>
#include <hip/hip_bf16.h>

// Fused: cvt(fp32->bf16, grid-stride) ; qkv-GEMM emitting Q(pre-scaled)/K/V in
// attn-native tiled layouts ; blockmasked 16-head attention with 32x32 MFMA,
// swapped QK^T, fully in-register softmax (cvt_pk+permlane32_swap), direct-L2
// tiled fragment loads, kv-split x4 ; out = attn @ w_fc^T.
// L=1152, D=1024, NH=16, DH=64, N_PC=1024.  (R12 config + micro-fixes)

typedef short bf16x8 __attribute__((ext_vector_type(8)));
typedef float f32x4 __attribute__((ext_vector_type(4)));
typedef float f32x16 __attribute__((ext_vector_type(16)));

#define L_SEQ   1152
#define NPC     1024
#define DMODEL  1024
#define TD      3072
#define NHEADS  16
#define DHEAD   64
#define NT32    36

__device__ __forceinline__ void gld_lds16(const void* g, void* l) {
  __builtin_amdgcn_global_load_lds((const __attribute__((address_space(1))) void*)g,
                                   (__attribute__((address_space(3))) void*)l,
                                   16, 0, 0);
}

template <int N>
__device__ __forceinline__ void s_wait_vmcnt() {
  if constexpr (N == 0)       asm volatile("s_waitcnt vmcnt(0)" ::: "memory");
  else if constexpr (N == 2)  asm volatile("s_waitcnt vmcnt(2)" ::: "memory");
  else if constexpr (N == 4)  asm volatile("s_waitcnt vmcnt(4)" ::: "memory");
  else if constexpr (N == 6)  asm volatile("s_waitcnt vmcnt(6)" ::: "memory");
  else if constexpr (N == 8)  asm volatile("s_waitcnt vmcnt(8)" ::: "memory");
  else if constexpr (N == 12) asm volatile("s_waitcnt vmcnt(12)" ::: "memory");
  else if constexpr (N == 16) asm volatile("s_waitcnt vmcnt(16)" ::: "memory");
  else static_assert(N == 0, "add vmcnt case");
}

// ---------------- fp32 -> bf16, grid-stride over all three tensors -------------
__global__ void cvt_all(const float* __restrict__ x, const float* __restrict__ wq,
                        const float* __restrict__ wf,
                        __hip_bfloat16* __restrict__ xb,
                        __hip_bfloat16* __restrict__ wqb,
                        __hip_bfloat16* __restrict__ wfb) {
  const int NX = 1152 * 1024 / 4, NQ = 3072 * 1024 / 4;
  const int NTOT = 5248 * 256;
  for (int i = blockIdx.x * blockDim.x + threadIdx.x; i < NTOT;
       i += gridDim.x * blockDim.x) {
    const float* s; __hip_bfloat16* d; int j;
    if (i < NX) { s = x; d = xb; j = i; }
    else if (i < NX + NQ) { s = wq; d = wqb; j = i - NX; }
    else { s = wf; d = wfb; j = i - NX - NQ; }
    float4 v = ((const float4*)s)[j];
    __align__(8) __hip_bfloat16 o[4];
    o[0] = __float2bfloat16(v.x);
    o[1] = __float2bfloat16(v.y);
    o[2] = __float2bfloat16(v.z);
    o[3] = __float2bfloat16(v.w);
    *(uint2*)&d[(size_t)j * 4] = *(const uint2*)o;
  }
}

// ---------------- bf16 GEMM: C[M,N] = A[M,K] * B[N,K]^T ----------------
// BM x BN tile, BK=64, 256 threads (4 waves 2x2). 3-buffer cyclic LDS pipeline,
// counted vmcnt. XOR-swizzled staging. Flat XCD-swizzled grid (column-chunked).
// MODE 0: C = float row-major.
// MODE 1: qkv GEMM. n<1024 -> Q tiled (scaled by 0.125*log2e); 1024..2047 -> K
// tiled; >=2048 -> V tiled.
template <int BM, int BN, int MODE, typename OT>
__global__ __launch_bounds__(256) void gemm_bt(
    const __hip_bfloat16* __restrict__ A,
    const __hip_bfloat16* __restrict__ B,
    OT* __restrict__ C,                    // MODE1: qT
    __hip_bfloat16* __restrict__ kT,
    __hip_bfloat16* __restrict__ vT,
    int M, int N, int K, int MT) {
  constexpr int WMT = BM / 2, WNT = BN / 2;
  constexpr int MI = WMT / 16, NI = WNT / 16;
  constexpr int ACH = BM * 8, BCH = BN * 8;
  constexpr int S = (ACH + BCH) / 256;
  __shared__ __align__(16) __hip_bfloat16 As[3][BM * 64];
  __shared__ __align__(16) __hip_bfloat16 Bs[3][BN * 64];

  const int tid = threadIdx.x, lane = tid & 63, w = tid >> 6;
  const int wm = w >> 1, wn = w & 1, l15 = lane & 15, lg = lane >> 4;
  const int chunk = (int)gridDim.x >> 3;
  const int wgid = ((int)blockIdx.x & 7) * chunk + ((int)blockIdx.x >> 3);
  const int m0 = (wgid % MT) * BM, n0 = (wgid / MT) * BN;

  f32x4 acc[MI][NI] = {};

  auto stage = [&](int b, int kt) {
    const __hip_bfloat16* Ag = A + (size_t)m0 * K + kt;
    const __hip_bfloat16* Bg = B + (size_t)n0 * K + kt;
#pragma unroll
    for (int c = tid; c < ACH; c += 256) {
      int r = c >> 3, gc = (c & 7) ^ (r & 7);
      gld_lds16(Ag + (size_t)r * K + gc * 8, &As[b][c * 8]);
    }
#pragma unroll
    for (int c = tid; c < BCH; c += 256) {
      int r = c >> 3, gc = (c & 7) ^ (r & 7);
      gld_lds16(Bg + (size_t)r * K + gc * 8, &Bs[b][c * 8]);
    }
  };

  const int NK = K >> 6;
  stage(0, 0);
  stage(1, 64);
  stage(2, 128);

  int buf = 0;
  for (int t = 0; t < NK; ++t) {
    if (t < NK - 2)       s_wait_vmcnt<2 * S>();
    else if (t == NK - 2) s_wait_vmcnt<S>();
    else                  s_wait_vmcnt<0>();
    __builtin_amdgcn_s_barrier();
    __builtin_amdgcn_sched_barrier(0);

#pragma unroll
    for (int kk = 0; kk < 2; ++kk) {
      bf16x8 af[MI], bfr[NI];
#pragma unroll
      for (int i = 0; i < MI; ++i) {
        int r = wm * WMT + i * 16 + l15;
        af[i] = *(const bf16x8*)&As[buf][(r * 8 + (((kk << 2) + lg) ^ (r & 7))) * 8];
      }
#pragma unroll
      for (int i = 0; i < NI; ++i) {
        int r = wn * WNT + i * 16 + l15;
        bfr[i] = *(const bf16x8*)&Bs[buf][(r * 8 + (((kk << 2) + lg) ^ (r & 7))) * 8];
      }
#pragma unroll
      for (int mi = 0; mi < MI; ++mi)
#pragma unroll
        for (int ni = 0; ni < NI; ++ni)
          acc[mi][ni] = __builtin_amdgcn_mfma_f32_16x16x32_bf16(
              af[mi], bfr[ni], acc[mi][ni], 0, 0, 0);
    }

    __builtin_amdgcn_sched_barrier(0);
    __builtin_amdgcn_s_barrier();
    __builtin_amdgcn_sched_barrier(0);
    if (t + 3 < NK) stage(buf, (t + 3) * 64);
    buf = (buf + 1 == 3) ? 0 : buf + 1;
  }

  // C/D layout (HW-verified m89): col = lane&15, row = (lane>>4)*4 + reg
  if constexpr (MODE == 0) {
#pragma unroll
    for (int mi = 0; mi < MI; ++mi)
#pragma unroll
      for (int ni = 0; ni < NI; ++ni) {
        int rb = m0 + wm * WMT + mi * 16 + lg * 4;
        int cb = n0 + wn * WNT + ni * 16 + l15;
#pragma unroll
        for (int r = 0; r < 4; ++r)
          C[(size_t)(rb + r) * N + cb] = acc[mi][ni][r];
      }
  } else if (n0 < 2 * DMODEL) {          // Q or K region -> tiled Q/K layout
    const bool isQ = (n0 < DMODEL);
    const float scl = isQ ? 0.18033688f : 1.0f;   // 0.125*log2(e)
    __hip_bfloat16* dst = isQ ? (__hip_bfloat16*)C : kT;
    const int nb = isQ ? n0 : (n0 - DMODEL);
    constexpr int TS2 = BN + 8;
    __hip_bfloat16* T = &As[0][0];
    __syncthreads();
#pragma unroll
    for (int mi = 0; mi < MI; ++mi)
#pragma unroll
      for (int ni = 0; ni < NI; ++ni) {
        int ml = wm * WMT + mi * 16 + lg * 4;
        int nl = wn * WNT + ni * 16 + l15;
#pragma unroll
        for (int r = 0; r < 4; ++r)
          T[(ml + r) * TS2 + nl] = __float2bfloat16(acc[mi][ni][r] * scl);
      }
    __syncthreads();
#pragma unroll
    for (int c = tid; c < (BM * BN) / 8; c += 256) {
      int ml = c >> 4, dc = c & 15;
      bf16x8 v = *(const bf16x8*)&T[ml * TS2 + dc * 8];
      int dfull = nb + dc * 8;
      int hh = dfull >> 6, dh = dfull & 63;
      int g = m0 + ml;
      size_t off = ((size_t)(hh * NT32 + (g >> 5))) * 2048 +
                   (size_t)((dh >> 4) * 64 + ((dh >> 3) & 1) * 32 + (g & 31)) * 8;
      *(bf16x8*)&dst[off] = v;
    }
  } else {                               // V region -> tiled V layout
    constexpr int TS = BM + 8;
    __hip_bfloat16* T = &As[0][0];
    __syncthreads();
#pragma unroll
    for (int mi = 0; mi < MI; ++mi)
#pragma unroll
      for (int ni = 0; ni < NI; ++ni) {
        int e = wn * WNT + ni * 16 + l15;     // d
        int l = wm * WMT + mi * 16 + lg * 4;  // kv
        __align__(8) __hip_bfloat16 o4[4];
#pragma unroll
        for (int r = 0; r < 4; ++r) o4[r] = __float2bfloat16(acc[mi][ni][r]);
        *(uint2*)&T[e * TS + l] = *(const uint2*)o4;
      }
    __syncthreads();
#pragma unroll
    for (int c = tid; c < (BN * BM) / 8; c += 256) {
      int dl = c >> 3, kvc = (c & 7) * 8;
      bf16x8 v = *(const bf16x8*)&T[dl * TS + kvc];
      int dfull = n0 - 2 * DMODEL + dl;
      int hh = dfull >> 6, dh = dfull & 63;
      int kvg = m0 + kvc;
      size_t off = ((size_t)(hh * NT32 + (kvg >> 5))) * 2048 +
                   (size_t)((((kvg >> 4) & 1) * 2 + (dh >> 5)) * 64 +
                            ((kvg >> 3) & 1) * 32 + (dh & 31)) * 8;
      *(bf16x8*)&vT[off] = v;
    }
  }
}

// ---------------- 32x32-MFMA attention, swapped QK^T, in-register softmax -----
// grid 576 XCD-swizzled (head = wgid/36). Block = (head, q32), 4 waves =
// kv-split x4. Per tile: S=mfma(K,Q) -> lane owns q=l&31, 16 kv scores ->
// exp2 -> cvt_pk+permlane32_swap -> PV mfma. No LDS until the final merge.
__global__ __launch_bounds__(256) void attn32(
    const __hip_bfloat16* __restrict__ qT,
    const __hip_bfloat16* __restrict__ kT,
    const __hip_bfloat16* __restrict__ vT,
    __hip_bfloat16* __restrict__ attnb) {
  const int wgid = ((int)blockIdx.x & 7) * 72 + ((int)blockIdx.x >> 3);
  const int h = wgid / NT32, qt = wgid % NT32;
  const int q0 = qt * 32;
  const int tid = threadIdx.x, lane = tid & 63, w = tid >> 6;
  const int l31 = lane & 31, hi = lane >> 5;

  __shared__ __align__(16) float Osh[4][32][68];   // ~34.8 KB
  __shared__ float Lsh[4][32];

  const __hip_bfloat16* qtp = qT + ((size_t)h * NT32 + qt) * 2048;
  bf16x8 qf0 = *(const bf16x8*)(qtp + (0 * 64 + lane) * 8);
  bf16x8 qf1 = *(const bf16x8*)(qtp + (1 * 64 + lane) * 8);
  bf16x8 qf2 = *(const bf16x8*)(qtp + (2 * 64 + lane) * 8);
  bf16x8 qf3 = *(const bf16x8*)(qtp + (3 * 64 + lane) * 8);

  const int q = q0 + l31;
  const int lim = (q < NPC) ? NPC : (q + 1);
  const int nst = (q0 < NPC) ? 32 : ((q0 + 32) >> 5);
  const int tbeg = (w * nst) / 4, tend = ((w + 1) * nst) / 4;

  const __hip_bfloat16* ktp = kT + (size_t)h * NT32 * 2048;
  const __hip_bfloat16* vtp = vT + (size_t)h * NT32 * 2048;

  float lsum = 0.f;
  f32x16 oA = {}, oB = {};                 // O d-halves [0,32) / [32,64)

  bf16x8 kA[4], vA[4], kB[4], vB[4];
  auto LD = [&](bf16x8 (&kf)[4], bf16x8 (&vf)[4], int t) {
    const __hip_bfloat16* kp = ktp + (size_t)t * 2048;
    const __hip_bfloat16* vp = vtp + (size_t)t * 2048;
#pragma unroll
    for (int c = 0; c < 4; ++c) kf[c] = *(const bf16x8*)(kp + (c * 64 + lane) * 8);
#pragma unroll
    for (int c = 0; c < 4; ++c) vf[c] = *(const bf16x8*)(vp + (c * 64 + lane) * 8);
  };

  auto BODY = [&](bf16x8 (&kf)[4], bf16x8 (&vf)[4], int t) {
    f32x16 S = {};
    __builtin_amdgcn_s_setprio(1);
    S = __builtin_amdgcn_mfma_f32_32x32x16_bf16(kf[0], qf0, S, 0, 0, 0);
    S = __builtin_amdgcn_mfma_f32_32x32x16_bf16(kf[1], qf1, S, 0, 0, 0);
    S = __builtin_amdgcn_mfma_f32_32x32x16_bf16(kf[2], qf2, S, 0, 0, 0);
    S = __builtin_amdgcn_mfma_f32_32x32x16_bf16(kf[3], qf3, S, 0, 0, 0);
    __builtin_amdgcn_s_setprio(0);
    const int kv0 = t << 5;
    float p[16];
#pragma unroll
    for (int r = 0; r < 16; ++r) p[r] = __builtin_amdgcn_exp2f(S[r]);
    if (kv0 >= NPC) {                      // mask live only in joint kv tiles
#pragma unroll
      for (int r = 0; r < 16; ++r) {
        int kv = kv0 + (r & 3) + 8 * (r >> 2) + 4 * hi;
        if (kv >= lim) p[r] = 0.f;
      }
    }
#pragma unroll
    for (int r = 0; r < 16; ++r) lsum += p[r];
    // P -> PV A-fragments: cvt_pk pairs + permlane32_swap (T12)
    unsigned W[8];
#pragma unroll
    for (int g = 0; g < 2; ++g) {
      unsigned x0, x1, y0, y1;
      asm("v_cvt_pk_bf16_f32 %0, %1, %2" : "=v"(x0) : "v"(p[g*8+0]), "v"(p[g*8+1]));
      asm("v_cvt_pk_bf16_f32 %0, %1, %2" : "=v"(x1) : "v"(p[g*8+4]), "v"(p[g*8+5]));
      asm("v_cvt_pk_bf16_f32 %0, %1, %2" : "=v"(y0) : "v"(p[g*8+2]), "v"(p[g*8+3]));
      asm("v_cvt_pk_bf16_f32 %0, %1, %2" : "=v"(y1) : "v"(p[g*8+6]), "v"(p[g*8+7]));
      asm("v_permlane32_swap_b32 %0, %1" : "+v"(x0), "+v"(x1));
      asm("v_permlane32_swap_b32 %0, %1" : "+v"(y0), "+v"(y1));
      W[g*4+0] = x0; W[g*4+1] = y0; W[g*4+2] = x1; W[g*4+3] = y1;
    }
    bf16x8 pa0, pa1;
    __builtin_memcpy(&pa0, &W[0], 16);
    __builtin_memcpy(&pa1, &W[4], 16);
    __builtin_amdgcn_s_setprio(1);
    oA = __builtin_amdgcn_mfma_f32_32x32x16_bf16(pa0, vf[0], oA, 0, 0, 0);
    oB = __builtin_amdgcn_mfma_f32_32x32x16_bf16(pa0, vf[1], oB, 0, 0, 0);
    oA = __builtin_amdgcn_mfma_f32_32x32x16_bf16(pa1, vf[2], oA, 0, 0, 0);
    oB = __builtin_amdgcn_mfma_f32_32x32x16_bf16(pa1, vf[3], oB, 0, 0, 0);
    __builtin_amdgcn_s_setprio(0);
  };

  LD(kA, vA, tbeg);
  int st = tbeg;
  for (; st + 2 <= tend; st += 2) {
    LD(kB, vB, st + 1);
    BODY(kA, vA, st);
    if (st + 2 < tend) LD(kA, vA, st + 2);   // no dummy tail reload
    BODY(kB, vB, st + 1);
  }
  if (st < tend) BODY(kA, vA, st);

  lsum += __shfl_xor(lsum, 32);            // combine kv-partials across hi pair

  // publish partials (no-max softmax: parts are additive)
#pragma unroll
  for (int r = 0; r < 16; ++r) {
    int qr = (r & 3) + 8 * (r >> 2) + 4 * hi;
    Osh[w][qr][l31] = oA[r];
    Osh[w][qr][32 + l31] = oB[r];
  }
  if (lane < 32) Lsh[w][l31] = lsum;
  __syncthreads();

  const int qq = tid >> 3, d8 = (tid & 7) * 8;
  float inv = 1.0f / (Lsh[0][qq] + Lsh[1][qq] + Lsh[2][qq] + Lsh[3][qq]);
  __align__(16) __hip_bfloat16 o8[8];
#pragma unroll
  for (int j = 0; j < 8; ++j) {
    float o = Osh[0][qq][d8 + j] + Osh[1][qq][d8 + j] +
              Osh[2][qq][d8 + j] + Osh[3][qq][d8 + j];
    o8[j] = __float2bfloat16(o * inv);
  }
  *(int4*)&attnb[(size_t)(q0 + qq) * DMODEL + h * DHEAD + d8] = *(const int4*)o8;
}

// ---------------- launch ----------------
extern "C" void kernel_launch(void* const* d_in, const int* in_sizes, int n_in,
                              void* d_out, int out_size, void* d_ws, size_t ws_size,
                              hipStream_t stream) {
  const float* x     = (const float*)d_in[0];
  const float* w_qkv = (const float*)d_in[1];
  const float* w_fc  = (const float*)d_in[2];
  float* out = (float*)d_out;

  char* ws = (char*)d_ws;
  __hip_bfloat16* xb    = (__hip_bfloat16*)(ws + 0);         // 2359296 B
  __hip_bfloat16* wqkvb = (__hip_bfloat16*)(ws + 2359296);   // 6291456 B
  __hip_bfloat16* wfcb  = (__hip_bfloat16*)(ws + 8650752);   // 2097152 B
  __hip_bfloat16* qTb   = (__hip_bfloat16*)(ws + 10747904);  // 2359296 B tiled Q
  __hip_bfloat16* kTb   = (__hip_bfloat16*)(ws + 13107200);  // 2359296 B tiled K
  __hip_bfloat16* vTb   = (__hip_bfloat16*)(ws + 15466496);  // 2359296 B tiled V
  __hip_bfloat16* attnb = (__hip_bfloat16*)(ws + 17825792);  // 2359296 B

  cvt_all<<<2048, 256, 0, stream>>>(x, w_qkv, w_fc, xb, wqkvb, wfcb);

  // qkv: Q (pre-scaled) / K / V emitted in attn tiled layouts
  gemm_bt<64, 128, 1, __hip_bfloat16><<<432, 256, 0, stream>>>(
      xb, wqkvb, qTb, kTb, vTb, L_SEQ, TD, DMODEL, 18);

  attn32<<<576, 256, 0, stream>>>(qTb, kTb, vTb, attnb);

  // out[l,e] = sum_d attn[l,d] * w_fc[e,d]
  gemm_bt<64, 64, 0, float><<<288, 256, 0, stream>>>(
      attnb, wfcb, out, nullptr, nullptr, L_SEQ, DMODEL, DMODEL, 18);
}